// Round 5
// baseline (2282.545 us; speedup 1.0000x reference)
//
#include <hip/hip_runtime.h>
#include <hip/hip_bf16.h>
#include <math.h>

// Tree-LSTM "LogicEncoder": D=10, N=1023 nodes, B=128, LD=256, K=2.
// Round 5: bf16x3 MFMA emulation for the big levels (8..5), fp32 elsewhere.
//  - Each fp32 split into 3 bf16 (8 significand bits each, trunc/trunc/round):
//    6 cross-products per MFMA accumulate into ONE fp32 acc -> ~2^-24 residual,
//    fp32-equivalent. The chaotic f*c recursion stays pure fp32 in epilogue.
//  - A (x|hL|hR) split on the fly during LDS staging (VALU hides under
//    LDS/MFMA per m114); W pre-split + transposed once (Wt[n][k] bf16 x3).
//  - Block: 1 node x 128 rows x 32 out-cols (x4 gate groups). 4 waves (2x2),
//    wave tile 64 rows x 4 group-tiles, 64 f32 acc/thread. K-step 32.
//  - Leaf + levels 4..0 keep round-4 proven fp32 kernels (incl. split-K tail).

#define NNODES 1023
#define BATCH  128
#define LDIM   256

typedef __attribute__((ext_vector_type(8))) short short8;
typedef __attribute__((ext_vector_type(4))) float f32x4;

__device__ __forceinline__ float sigmoidf_(float x) {
    return 1.f / (1.f + expf(-x));
}

// fp32 -> 3x bf16 split: hi,mid = truncation (exact residuals), lo = rounded.
__device__ __forceinline__ void split3(float x, ushort& h, ushort& m, ushort& l) {
    unsigned u = __float_as_uint(x);
    float hf = __uint_as_float(u & 0xFFFF0000u);
    h = (ushort)(u >> 16);
    float r = x - hf;
    unsigned ur = __float_as_uint(r);
    float mf = __uint_as_float(ur & 0xFFFF0000u);
    m = (ushort)(ur >> 16);
    float r2 = r - mf;
    l = (ushort)((__float_as_uint(r2) + 0x8000u) >> 16);
}

// ---------------------------------------------------------------------------
// Pack Wbig (768x1024) + bias_big(1024) + Wleaf(256x512) + bias_leaf(512).
__global__ __launch_bounds__(256) void build_weights(
    const float* __restrict__ Wix, const float* __restrict__ bix,
    const float* __restrict__ Wfx, const float* __restrict__ bfx,
    const float* __restrict__ Wux, const float* __restrict__ bux,
    const float* __restrict__ Wi,  const float* __restrict__ bi,
    const float* __restrict__ Wf,  const float* __restrict__ bf,
    const float* __restrict__ Wu,  const float* __restrict__ bu,
    const float* __restrict__ Wcx, const float* __restrict__ bcx,
    const float* __restrict__ Wox, const float* __restrict__ box,
    float* __restrict__ Wbig, float* __restrict__ bias_big,
    float* __restrict__ Wleaf, float* __restrict__ bias_leaf)
{
    int i = blockIdx.x * blockDim.x + threadIdx.x;
    if (i < 768 * 1024) {
        int k = i >> 10, n = i & 1023;
        int g = n >> 8, nn = n & 255;
        float v;
        if (g == 0) {
            v = (k < 256) ? Wix[k * 256 + nn]
              : (k < 512) ? Wi[(k - 256) * 256 + nn]
                          : Wi[65536 + (k - 512) * 256 + nn];
        } else if (g == 1) {
            v = (k < 256) ? Wux[k * 256 + nn]
              : (k < 512) ? Wu[(k - 256) * 256 + nn]
                          : Wu[65536 + (k - 512) * 256 + nn];
        } else {
            int kf = g - 2;  // f0 / f1
            v = (k < 256) ? Wfx[k * 256 + nn]
              : (k < 512) ? Wf[((kf * 2 + 0) * 256 + (k - 256)) * 256 + nn]
                          : Wf[((kf * 2 + 1) * 256 + (k - 512)) * 256 + nn];
        }
        Wbig[i] = v;
        return;
    }
    i -= 768 * 1024;
    if (i < 1024) {
        int g = i >> 8, nn = i & 255;
        float v;
        if (g == 0)      v = bix[nn] + bi[nn] + bi[256 + nn];
        else if (g == 1) v = bux[nn] + bu[nn] + bu[256 + nn];
        else if (g == 2) v = bfx[nn] + bf[nn] + bf[256 + nn];
        else             v = bfx[nn] + bf[512 + nn] + bf[768 + nn];
        bias_big[i] = v;
        return;
    }
    i -= 1024;
    if (i < 256 * 512) {
        int k = i >> 9, n = i & 511;
        Wleaf[i] = (n < 256) ? Wcx[k * 256 + n] : Wox[k * 256 + (n - 256)];
        return;
    }
    i -= 256 * 512;
    if (i < 512) {
        bias_leaf[i] = (i < 256) ? bcx[i] : box[i - 256];
    }
}

// ---------------------------------------------------------------------------
// Split Wbig into 3 bf16 planes TRANSPOSED: Wt_s[n][k] (1024 x 768).
// grid (24, 32) = (768/32, 1024/32), block 256, LDS tile transpose.
__global__ __launch_bounds__(256) void split_weights_T(
    const float* __restrict__ Wbig,
    ushort* __restrict__ Wth, ushort* __restrict__ Wtm, ushort* __restrict__ Wtl)
{
    __shared__ float sh[32][33];
    const int k0 = blockIdx.x * 32, n0 = blockIdx.y * 32;
    const int t = threadIdx.x;
    {
        int r = t >> 3, c4 = (t & 7) * 4;
        float4 v = *(const float4*)&Wbig[(size_t)(k0 + r) * 1024 + n0 + c4];
        sh[r][c4] = v.x; sh[r][c4 + 1] = v.y; sh[r][c4 + 2] = v.z; sh[r][c4 + 3] = v.w;
    }
    __syncthreads();
    int n = t >> 3, kc = (t & 7) * 4;
    ushort oh[4], om[4], ol[4];
#pragma unroll
    for (int j = 0; j < 4; ++j)
        split3(sh[kc + j][n], oh[j], om[j], ol[j]);
    size_t o = (size_t)(n0 + n) * 768 + k0 + kc;
    *(ushort4*)&Wth[o] = make_ushort4(oh[0], oh[1], oh[2], oh[3]);
    *(ushort4*)&Wtm[o] = make_ushort4(om[0], om[1], om[2], om[3]);
    *(ushort4*)&Wtl[o] = make_ushort4(ol[0], ol[1], ol[2], ol[3]);
}

// ---------------------------------------------------------------------------
// bf16x3 MFMA level kernel. grid (W nodes, 8), block 256 (4 waves, 2x2).
// Block: node bx, out-cols [gy*32, gy*32+32) across all 4 gate groups.
// Wave (mi,ni): rows [mi*64, +64), cols [ni*16, +16); tiles: 4 Mt x 4 groups.
__global__ __launch_bounds__(256) void mfma_level(
    const float* __restrict__ x_embed,
    const float* __restrict__ hChild, const float* __restrict__ cChild,
    const ushort* __restrict__ Wth, const ushort* __restrict__ Wtm,
    const ushort* __restrict__ Wtl,
    const float* __restrict__ bias,
    float* __restrict__ hOut, float* __restrict__ cOut, int nstart)
{
    constexpr int AST = 40;                       // ushort stride per row/col
    __shared__ __align__(16) ushort Alds[3][128 * AST];
    __shared__ __align__(16) ushort Blds[3][128 * AST];

    const int tid  = threadIdx.x;
    const int node = blockIdx.x, gy = blockIdx.y;
    const int lane = tid & 63, wid = tid >> 6;
    const int mi = wid >> 1, ni = wid & 1;
    const int srow = tid >> 1, shalf = tid & 1;   // staging row/half

    // A sources (fp32, split on the fly). Row = batch b = srow.
    const float* aX = x_embed + ((size_t)srow * NNODES + (nstart + node)) * LDIM;
    const float* aL = hChild + ((size_t)(2 * node) * BATCH + srow) * LDIM;
    const float* aR = aL + (size_t)BATCH * LDIM;
    // B source: LDS col c = srow -> n = (c>>5)*256 + gy*32 + (c&31).
    const size_t nb = (size_t)(((srow >> 5) << 8) + gy * 32 + (srow & 31)) * 768;
    const ushort* b0 = Wth + nb;
    const ushort* b1 = Wtm + nb;
    const ushort* b2 = Wtl + nb;

    f32x4 acc[4][4];
#pragma unroll
    for (int a = 0; a < 4; ++a)
#pragma unroll
        for (int g = 0; g < 4; ++g) acc[a][g] = (f32x4){0.f, 0.f, 0.f, 0.f};

    float aS[16];
    int4  bS[3][2];

    auto LOADS = [&](int it) {
        const int seg = it >> 3;
        const int koff = (it & 7) * 32 + shalf * 16;
        const float* ap = (seg == 0) ? aX : (seg == 1) ? aL : aR;
        ap += koff;
#pragma unroll
        for (int q = 0; q < 4; ++q)
            *(float4*)&aS[q * 4] = *(const float4*)(ap + q * 4);
        const int bko = it * 32 + shalf * 16;
        bS[0][0] = *(const int4*)(b0 + bko); bS[0][1] = *(const int4*)(b0 + bko + 8);
        bS[1][0] = *(const int4*)(b1 + bko); bS[1][1] = *(const int4*)(b1 + bko + 8);
        bS[2][0] = *(const int4*)(b2 + bko); bS[2][1] = *(const int4*)(b2 + bko + 8);
    };
    auto WRITE = [&]() {
        unsigned pk[3][8];
#pragma unroll
        for (int e = 0; e < 16; ++e) {
            ushort a, m, l;
            split3(aS[e], a, m, l);
            if (e & 1) {
                pk[0][e >> 1] |= (unsigned)a << 16;
                pk[1][e >> 1] |= (unsigned)m << 16;
                pk[2][e >> 1] |= (unsigned)l << 16;
            } else {
                pk[0][e >> 1] = a; pk[1][e >> 1] = m; pk[2][e >> 1] = l;
            }
        }
        const int base = srow * AST + shalf * 16;
#pragma unroll
        for (int s = 0; s < 3; ++s) {
            *(int4*)&Alds[s][base]     = make_int4(pk[s][0], pk[s][1], pk[s][2], pk[s][3]);
            *(int4*)&Alds[s][base + 8] = make_int4(pk[s][4], pk[s][5], pk[s][6], pk[s][7]);
            *(int4*)&Blds[s][base]     = bS[s][0];
            *(int4*)&Blds[s][base + 8] = bS[s][1];
        }
    };
    auto COMPUTE = [&]() {
        short8 af[4][3];
#pragma unroll
        for (int Mt = 0; Mt < 4; ++Mt) {
            const int rb = (mi * 64 + Mt * 16 + (lane & 15)) * AST + (lane >> 4) * 8;
#pragma unroll
            for (int s = 0; s < 3; ++s) af[Mt][s] = *(const short8*)&Alds[s][rb];
        }
#pragma unroll
        for (int g = 0; g < 4; ++g) {
            const int cb = (g * 32 + ni * 16 + (lane & 15)) * AST + (lane >> 4) * 8;
            short8 bh = *(const short8*)&Blds[0][cb];
            short8 bm = *(const short8*)&Blds[1][cb];
            short8 bl = *(const short8*)&Blds[2][cb];
            // small -> large accumulation order
#pragma unroll
            for (int Mt = 0; Mt < 4; ++Mt)
                acc[Mt][g] = __builtin_amdgcn_mfma_f32_16x16x32_bf16(af[Mt][0], bl, acc[Mt][g], 0, 0, 0);
#pragma unroll
            for (int Mt = 0; Mt < 4; ++Mt)
                acc[Mt][g] = __builtin_amdgcn_mfma_f32_16x16x32_bf16(af[Mt][2], bh, acc[Mt][g], 0, 0, 0);
#pragma unroll
            for (int Mt = 0; Mt < 4; ++Mt)
                acc[Mt][g] = __builtin_amdgcn_mfma_f32_16x16x32_bf16(af[Mt][1], bm, acc[Mt][g], 0, 0, 0);
#pragma unroll
            for (int Mt = 0; Mt < 4; ++Mt)
                acc[Mt][g] = __builtin_amdgcn_mfma_f32_16x16x32_bf16(af[Mt][0], bm, acc[Mt][g], 0, 0, 0);
#pragma unroll
            for (int Mt = 0; Mt < 4; ++Mt)
                acc[Mt][g] = __builtin_amdgcn_mfma_f32_16x16x32_bf16(af[Mt][1], bh, acc[Mt][g], 0, 0, 0);
#pragma unroll
            for (int Mt = 0; Mt < 4; ++Mt)
                acc[Mt][g] = __builtin_amdgcn_mfma_f32_16x16x32_bf16(af[Mt][0], bh, acc[Mt][g], 0, 0, 0);
        }
    };

    LOADS(0);
    for (int it = 0; it < 24; ++it) {
        if (it) __syncthreads();
        WRITE();
        __syncthreads();
        if (it + 1 < 24) LOADS(it + 1);
        COMPUTE();
    }

    // ----- fused LSTM epilogue (pure fp32 c-path) -----
    const int col = gy * 32 + ni * 16 + (lane & 15);     // 0..255
    const int rq  = (lane >> 4) * 4;
    const size_t cLb = (size_t)(2 * node) * BATCH * LDIM;
    const size_t cRb = cLb + (size_t)BATCH * LDIM;
    const size_t ob  = (size_t)node * BATCH * LDIM;
    const float bi_ = bias[col], bu_ = bias[256 + col];
    const float bf0 = bias[512 + col], bf1 = bias[768 + col];
#pragma unroll
    for (int Mt = 0; Mt < 4; ++Mt) {
#pragma unroll
        for (int j = 0; j < 4; ++j) {
            const int row = mi * 64 + Mt * 16 + rq + j;  // batch b
            float gi = sigmoidf_(acc[Mt][0][j] + bi_);
            float gu = tanhf(acc[Mt][1][j] + bu_);
            float f0 = acc[Mt][2][j] + bf0;
            float f1 = acc[Mt][3][j] + bf1;
            float cL = cChild[cLb + (size_t)row * LDIM + col];
            float cR = cChild[cRb + (size_t)row * LDIM + col];
            float c  = gi * gu + f0 * cL + f1 * cR;
            cOut[ob + (size_t)row * LDIM + col] = c;
            hOut[ob + (size_t)row * LDIM + col] = tanhf(c);
        }
    }
}

// ---------------------------------------------------------------------------
// Leaf kernel (round-1/4 proven). grid (1024, 4), block 256.
__global__ __launch_bounds__(256) void leaf_kernel(
    const float* __restrict__ x_embed,
    const float* __restrict__ Wleaf, const float* __restrict__ bias_leaf,
    float* __restrict__ hOut, float* __restrict__ cOut)
{
    __shared__ float As[16 * 68];
    __shared__ float Bs[2 * 16 * 64];
    float acc[2][4][4] = {};
    const int tid = threadIdx.x;
    const int ty = tid >> 4, tx = tid & 15;
    const int row0 = blockIdx.x * 64;
    const int n0 = blockIdx.y * 64;
    const int w = row0 >> 7;
    const int ar = tid >> 2;
    const int kq = (tid & 3) * 4;
    const int b = (row0 + ar) & 127;
    const float* xrow = x_embed + ((size_t)b * NNODES + 511 + w) * LDIM;

    for (int k0 = 0; k0 < 256; k0 += 16) {
        float4 av = *(const float4*)(xrow + k0 + kq);
        As[(kq + 0) * 68 + ar] = av.x;
        As[(kq + 1) * 68 + ar] = av.y;
        As[(kq + 2) * 68 + ar] = av.z;
        As[(kq + 3) * 68 + ar] = av.w;
#pragma unroll
        for (int q = 0; q < 2; ++q) {
            int L = q * 256 + tid;
            int g = L >> 8, kk = (L >> 4) & 15, n4 = (L & 15) * 4;
            float4 bv = *(const float4*)(Wleaf + (size_t)(k0 + kk) * 512 + g * 256 + n0 + n4);
            *(float4*)&Bs[(g * 16 + kk) * 64 + n4] = bv;
        }
        __syncthreads();
#pragma unroll
        for (int kk = 0; kk < 16; ++kk) {
            float4 a = *(const float4*)&As[kk * 68 + ty * 4];
            float av4[4] = {a.x, a.y, a.z, a.w};
#pragma unroll
            for (int g = 0; g < 2; ++g) {
                float4 bb = *(const float4*)&Bs[(g * 16 + kk) * 64 + tx * 4];
                float bv4[4] = {bb.x, bb.y, bb.z, bb.w};
#pragma unroll
                for (int ii = 0; ii < 4; ++ii)
#pragma unroll
                    for (int jj = 0; jj < 4; ++jj)
                        acc[g][ii][jj] += av4[ii] * bv4[jj];
            }
        }
        __syncthreads();
    }
#pragma unroll
    for (int ii = 0; ii < 4; ++ii) {
        int r = row0 + ty * 4 + ii;
        int nc = n0 + tx * 4;
        float4 c4, h4;
        float* cp = (float*)&c4; float* hp = (float*)&h4;
#pragma unroll
        for (int jj = 0; jj < 4; ++jj) {
            int n = nc + jj;
            float ac = acc[0][ii][jj] + bias_leaf[n];
            float ao = acc[1][ii][jj] + bias_leaf[256 + n];
            cp[jj] = ac;
            hp[jj] = sigmoidf_(ao) * tanhf(ac);
        }
        *(float4*)&cOut[(size_t)r * LDIM + nc] = c4;
        *(float4*)&hOut[(size_t)r * LDIM + nc] = h4;
    }
}

// ---------------------------------------------------------------------------
// fp32 level kernel (round-1/4 proven). grid (W*2, 4), block 256.
__global__ __launch_bounds__(256) void level_kernel(
    const float* __restrict__ x_embed,
    const float* __restrict__ hChild, const float* __restrict__ cChild,
    const float* __restrict__ Wbig, const float* __restrict__ bias_big,
    float* __restrict__ hOut, float* __restrict__ cOut,
    int nstart)
{
    __shared__ float As[16 * 68];
    __shared__ float Bs[4 * 16 * 64];
    float acc[4][4][4] = {};
    const int tid = threadIdx.x;
    const int ty = tid >> 4, tx = tid & 15;
    const int row0 = blockIdx.x * 64;
    const int n0 = blockIdx.y * 64;
    const int w = row0 >> 7;
    const int ar = tid >> 2;
    const int kq = (tid & 3) * 4;
    const int b = (row0 + ar) & 127;
    const float* srcX = x_embed + ((size_t)b * NNODES + nstart + w) * LDIM;
    const float* srcL = hChild + ((size_t)(2 * w) * BATCH + b) * LDIM;
    const float* srcR = hChild + ((size_t)(2 * w + 1) * BATCH + b) * LDIM;

    for (int k0 = 0; k0 < 768; k0 += 16) {
        int seg = k0 >> 8, off = k0 & 255;
        const float* src = (seg == 0) ? srcX : (seg == 1) ? srcL : srcR;
        float4 av = *(const float4*)(src + off + kq);
        As[(kq + 0) * 68 + ar] = av.x;
        As[(kq + 1) * 68 + ar] = av.y;
        As[(kq + 2) * 68 + ar] = av.z;
        As[(kq + 3) * 68 + ar] = av.w;
#pragma unroll
        for (int q = 0; q < 4; ++q) {
            int L = q * 256 + tid;
            int g = L >> 8, kk = (L >> 4) & 15, n4 = (L & 15) * 4;
            float4 bv = *(const float4*)(Wbig + (size_t)(k0 + kk) * 1024 + g * 256 + n0 + n4);
            *(float4*)&Bs[(g * 16 + kk) * 64 + n4] = bv;
        }
        __syncthreads();
#pragma unroll
        for (int kk = 0; kk < 16; ++kk) {
            float4 a = *(const float4*)&As[kk * 68 + ty * 4];
            float av4[4] = {a.x, a.y, a.z, a.w};
#pragma unroll
            for (int g = 0; g < 4; ++g) {
                float4 bb = *(const float4*)&Bs[(g * 16 + kk) * 64 + tx * 4];
                float bv4[4] = {bb.x, bb.y, bb.z, bb.w};
#pragma unroll
                for (int ii = 0; ii < 4; ++ii)
#pragma unroll
                    for (int jj = 0; jj < 4; ++jj)
                        acc[g][ii][jj] += av4[ii] * bv4[jj];
            }
        }
        __syncthreads();
    }
    const size_t cLbase = ((size_t)(2 * w) * BATCH) * LDIM;
    const size_t cRbase = ((size_t)(2 * w + 1) * BATCH) * LDIM;
#pragma unroll
    for (int ii = 0; ii < 4; ++ii) {
        int r = row0 + ty * 4 + ii;
        int bb2 = r & 127;
        int nc = n0 + tx * 4;
        float4 cL = *(const float4*)&cChild[cLbase + (size_t)bb2 * LDIM + nc];
        float4 cR = *(const float4*)&cChild[cRbase + (size_t)bb2 * LDIM + nc];
        float cl4[4] = {cL.x, cL.y, cL.z, cL.w};
        float cr4[4] = {cR.x, cR.y, cR.z, cR.w};
        float4 c4, h4;
        float* cp = (float*)&c4; float* hp = (float*)&h4;
#pragma unroll
        for (int jj = 0; jj < 4; ++jj) {
            int n = nc + jj;
            float gi = sigmoidf_(acc[0][ii][jj] + bias_big[n]);
            float gu = tanhf(acc[1][ii][jj] + bias_big[256 + n]);
            float f0 = acc[2][ii][jj] + bias_big[512 + n];
            float f1 = acc[3][ii][jj] + bias_big[768 + n];
            float c = gi * gu + f0 * cl4[jj] + f1 * cr4[jj];
            cp[jj] = c;
            hp[jj] = tanhf(c);
        }
        *(float4*)&cOut[(size_t)r * LDIM + nc] = c4;
        *(float4*)&hOut[(size_t)r * LDIM + nc] = h4;
    }
}

// ---------------------------------------------------------------------------
// Split-K partial (TM=4, one 256-wide K segment per blockIdx.z). grid (W*2,4,3).
__global__ __launch_bounds__(256) void gemm_part4(
    const float* __restrict__ x_embed, const float* __restrict__ hChild,
    const float* __restrict__ Wbig,
    float* __restrict__ part, int nstart, int rowsTotal)
{
    __shared__ float As[16 * 68];
    __shared__ float Bs[4 * 16 * 64];
    float acc[4][4][4] = {};
    const int tid = threadIdx.x;
    const int ty = tid >> 4, tx = tid & 15;
    const int row0 = blockIdx.x * 64;
    const int n0 = blockIdx.y * 64;
    const int seg = blockIdx.z;
    const int w = row0 >> 7;
    const int ar = tid >> 2;
    const int kq = (tid & 3) * 4;
    const int b = (row0 + ar) & 127;
    const float* src =
        (seg == 0) ? x_embed + ((size_t)b * NNODES + nstart + w) * LDIM
                   : hChild + ((size_t)(2 * w + (seg - 1)) * BATCH + b) * LDIM;

    for (int k0 = 0; k0 < 256; k0 += 16) {
        float4 av = *(const float4*)(src + k0 + kq);
        As[(kq + 0) * 68 + ar] = av.x;
        As[(kq + 1) * 68 + ar] = av.y;
        As[(kq + 2) * 68 + ar] = av.z;
        As[(kq + 3) * 68 + ar] = av.w;
#pragma unroll
        for (int q = 0; q < 4; ++q) {
            int L = q * 256 + tid;
            int g = L >> 8, kk = (L >> 4) & 15, n4 = (L & 15) * 4;
            float4 bv = *(const float4*)(Wbig + (size_t)(seg * 256 + k0 + kk) * 1024
                                         + g * 256 + n0 + n4);
            *(float4*)&Bs[(g * 16 + kk) * 64 + n4] = bv;
        }
        __syncthreads();
#pragma unroll
        for (int kk = 0; kk < 16; ++kk) {
            float4 a = *(const float4*)&As[kk * 68 + ty * 4];
            float av4[4] = {a.x, a.y, a.z, a.w};
#pragma unroll
            for (int g = 0; g < 4; ++g) {
                float4 bb = *(const float4*)&Bs[(g * 16 + kk) * 64 + tx * 4];
                float bv4[4] = {bb.x, bb.y, bb.z, bb.w};
#pragma unroll
                for (int ii = 0; ii < 4; ++ii)
#pragma unroll
                    for (int jj = 0; jj < 4; ++jj)
                        acc[g][ii][jj] += av4[ii] * bv4[jj];
            }
        }
        __syncthreads();
    }
#pragma unroll
    for (int ii = 0; ii < 4; ++ii) {
        int r = row0 + ty * 4 + ii;
        size_t base = ((size_t)seg * rowsTotal + r) * 1024 + n0 + tx * 4;
#pragma unroll
        for (int g = 0; g < 4; ++g)
            *(float4*)&part[base + g * 256] = *(float4*)acc[g][ii];
    }
}

// ---------------------------------------------------------------------------
// Combine 3 split-K partials + LSTM epilogue. grid (rows/4), block 256.
__global__ __launch_bounds__(256) void combine_eps(
    const float* __restrict__ part, const float* __restrict__ cChild,
    const float* __restrict__ bias,
    float* __restrict__ hOut, float* __restrict__ cOut, int rowsTotal)
{
    int idx = blockIdx.x * 256 + threadIdx.x;
    int row = idx >> 6, n = (idx & 63) * 4;
    size_t sseg = (size_t)rowsTotal * 1024;
    const float* p0 = part + (size_t)row * 1024 + n;
    float s[4][4];
#pragma unroll
    for (int g = 0; g < 4; ++g) {
        float4 a = *(const float4*)(p0 + g * 256);
        float4 b = *(const float4*)(p0 + sseg + g * 256);
        float4 c = *(const float4*)(p0 + 2 * sseg + g * 256);
        s[g][0] = a.x + b.x + c.x; s[g][1] = a.y + b.y + c.y;
        s[g][2] = a.z + b.z + c.z; s[g][3] = a.w + b.w + c.w;
    }
    int node = row >> 7, b = row & 127;
    float4 cL = *(const float4*)&cChild[((size_t)(2 * node) * BATCH + b) * LDIM + n];
    float4 cR = *(const float4*)&cChild[((size_t)(2 * node + 1) * BATCH + b) * LDIM + n];
    float cl4[4] = {cL.x, cL.y, cL.z, cL.w};
    float cr4[4] = {cR.x, cR.y, cR.z, cR.w};
    float4 c4, h4;
    float* cp = (float*)&c4; float* hp = (float*)&h4;
#pragma unroll
    for (int jj = 0; jj < 4; ++jj) {
        int nn = n + jj;
        float gi = sigmoidf_(s[0][jj] + bias[nn]);
        float gu = tanhf(s[1][jj] + bias[256 + nn]);
        float f0 = s[2][jj] + bias[512 + nn];
        float f1 = s[3][jj] + bias[768 + nn];
        float c = gi * gu + f0 * cl4[jj] + f1 * cr4[jj];
        cp[jj] = c;
        hp[jj] = tanhf(c);
    }
    *(float4*)&cOut[(size_t)row * LDIM + n] = c4;
    *(float4*)&hOut[(size_t)row * LDIM + n] = h4;
}

// ---------------------------------------------------------------------------
// Final: out[b][n] = tanh([init | c_root | h_root] @ Woend + boend). grid 128.
__global__ __launch_bounds__(256) void final_kernel(
    const float* __restrict__ init_emb,
    const float* __restrict__ cRoot, const float* __restrict__ hRoot,
    const float* __restrict__ Woend, const float* __restrict__ boend,
    float* __restrict__ out)
{
    __shared__ float sv[768];
    int b = blockIdx.x, t = threadIdx.x;
    sv[t]       = init_emb[(size_t)b * 256 + t];
    sv[256 + t] = cRoot[(size_t)b * 256 + t];
    sv[512 + t] = hRoot[(size_t)b * 256 + t];
    __syncthreads();
    float acc = boend[t];
#pragma unroll 4
    for (int d = 0; d < 768; ++d)
        acc += sv[d] * Woend[(size_t)d * 256 + t];
    out[(size_t)b * 256 + t] = tanhf(acc);
}

// ---------------------------------------------------------------------------
extern "C" void kernel_launch(void* const* d_in, const int* in_sizes, int n_in,
                              void* d_out, int out_size, void* d_ws, size_t ws_size,
                              hipStream_t stream)
{
    const float* x_embed  = (const float*)d_in[0];
    const float* init_emb = (const float*)d_in[1];
    const float* Wcx = (const float*)d_in[2];  const float* bcx = (const float*)d_in[3];
    const float* Wox = (const float*)d_in[4];  const float* box = (const float*)d_in[5];
    const float* Wix = (const float*)d_in[6];  const float* bix = (const float*)d_in[7];
    const float* Wfx = (const float*)d_in[8];  const float* bfx = (const float*)d_in[9];
    const float* Wux = (const float*)d_in[10]; const float* bux = (const float*)d_in[11];
    const float* Wi  = (const float*)d_in[12]; const float* bi  = (const float*)d_in[13];
    const float* Wf  = (const float*)d_in[14]; const float* bf  = (const float*)d_in[15];
    const float* Wu  = (const float*)d_in[16]; const float* bu  = (const float*)d_in[17];
    const float* Woend = (const float*)d_in[18]; const float* boend = (const float*)d_in[19];
    float* out = (float*)d_out;
    float* ws  = (float*)d_ws;

    size_t off = 0;
    float* hA = ws + off; off += (size_t)512 * 128 * 256;
    float* cA = ws + off; off += (size_t)512 * 128 * 256;
    float* hB = ws + off; off += (size_t)256 * 128 * 256;
    float* cB = ws + off; off += (size_t)256 * 128 * 256;
    float* Wbig      = ws + off; off += (size_t)768 * 1024;
    float* bias_big  = ws + off; off += 1024;
    float* Wleaf     = ws + off; off += (size_t)256 * 512;
    float* bias_leaf = ws + off; off += 512;
    // bf16 weight splits, transposed [n][k] (carved from float space)
    ushort* Wth = (ushort*)(ws + off); off += (size_t)768 * 1024 / 2;
    ushort* Wtm = (ushort*)(ws + off); off += (size_t)768 * 1024 / 2;
    ushort* Wtl = (ushort*)(ws + off); off += (size_t)768 * 1024 / 2;
    size_t mfma_need = off * sizeof(float);
    size_t part_off = off;
    float* part = ws + part_off;

    bool mfma_ok = mfma_need <= ws_size;

    {
        int total = 768 * 1024 + 1024 + 256 * 512 + 512;
        int blocks = (total + 255) / 256;
        build_weights<<<blocks, 256, 0, stream>>>(
            Wix, bix, Wfx, bfx, Wux, bux, Wi, bi, Wf, bf, Wu, bu,
            Wcx, bcx, Wox, box, Wbig, bias_big, Wleaf, bias_leaf);
    }
    if (mfma_ok) {
        split_weights_T<<<dim3(24, 32), 256, 0, stream>>>(Wbig, Wth, Wtm, Wtl);
    }

    leaf_kernel<<<dim3(1024, 4), 256, 0, stream>>>(x_embed, Wleaf, bias_leaf, hA, cA);

    float* hbufs[2] = {hA, hB};
    float* cbufs[2] = {cA, cB};
    int child = 0;  // leaves in A
    for (int lvl = 8; lvl >= 0; --lvl) {
        int W = 1 << lvl, s = W - 1;
        int outb = child ^ 1;
        size_t rows = (size_t)W * 128;
        bool split = (W <= 16) &&
                     ((part_off + 3 * rows * 1024) * sizeof(float) <= ws_size);
        if (lvl >= 5 && mfma_ok) {
            mfma_level<<<dim3(W, 8), 256, 0, stream>>>(
                x_embed, hbufs[child], cbufs[child], Wth, Wtm, Wtl, bias_big,
                hbufs[outb], cbufs[outb], s);
        } else if (split) {
            gemm_part4<<<dim3(W * 2, 4, 3), 256, 0, stream>>>(
                x_embed, hbufs[child], Wbig, part, s, (int)rows);
            combine_eps<<<(int)(rows / 4), 256, 0, stream>>>(
                part, cbufs[child], bias_big, hbufs[outb], cbufs[outb], (int)rows);
        } else {
            level_kernel<<<dim3(W * 2, 4), 256, 0, stream>>>(
                x_embed, hbufs[child], cbufs[child], Wbig, bias_big,
                hbufs[outb], cbufs[outb], s);
        }
        child = outb;
    }

    final_kernel<<<128, 256, 0, stream>>>(init_emb, cbufs[child], hbufs[child],
                                          Woend, boend, out);
}